// Round 4
// baseline (372.525 us; speedup 1.0000x reference)
//
#include <hip/hip_runtime.h>

// VersorRotorRNN: B=16, S=256, N=16, D=6, H=16, 32 blades (Cl(5,0)).
// Segmented parallel scan over S. normalize() is scale-invariant and the
// geometric product is bilinear+associative, so psi_t = N(dr_t (x) ... (x) dr_1)
// with dr unnormalized and all intermediate normalizations deferrable.
//
// R2 lesson: forcing min-waves=2 via __launch_bounds__ spilled (FETCH 443MB).
// R3 lesson: uu[32]+R[32]+np[32]+WO staging live together -> VGPR 256 + spill
//            (WRITE 39MB) -> 1 wave/SIMD, VALUBusy 31%.
// R4 fix: STREAM the u operand in 8-elem chunks fused into the GP; live set
//         ~R[32]+np[32]+u8[8]+misc ~ 130 VGPR -> no spill, 2 waves/SIMD.

#define EPS 1e-8f

// --- compile-time Cayley sign table: sgn(i,j) for C[i,j,i^j] ---
struct SgnTab { float v[32][32]; };
constexpr SgnTab make_sgn() {
    SgnTab t{};
    for (int i = 0; i < 32; ++i)
        for (int j = 0; j < 32; ++j) {
            int a = i >> 1, s = 0;
            while (a) {
                int x = a & j;
                while (x) { s += x & 1; x >>= 1; }
                a >>= 1;
            }
            t.v[i][j] = (s & 1) ? -1.0f : 1.0f;
        }
    return t;
}
__device__ constexpr SgnTab SG = make_sgn();

__device__ __forceinline__ float inv_norm(const float* v) {
    float s0 = 0.f, s1 = 0.f, s2 = 0.f, s3 = 0.f;
#pragma unroll
    for (int k = 0; k < 32; k += 4) {
        s0 = fmaf(v[k],     v[k],     s0);
        s1 = fmaf(v[k + 1], v[k + 1], s1);
        s2 = fmaf(v[k + 2], v[k + 2], s2);
        s3 = fmaf(v[k + 3], v[k + 3], s3);
    }
    return rsqrtf((s0 + s1) + (s2 + s3) + EPS);
}

// LDS layouts (per-h, b128-friendly):
//   WIN: stride 196 floats/h: [h*196 + d*32 + c]   (196%32==4 -> rows h,h+8
//   BIN: stride  36 floats/h: [h*36 + c]            share banks = 2-way = free;
//   WOU: stride 196 floats/h: [h*196 + k*6 + d]     196%4==0 -> 16B aligned)
#define WIN_STRIDE 196
#define BIN_STRIDE 36

// build u8 = chunk c8 (8 blades) of  b_in[h] + x . W_in[:,h*32+...]  (+1 on blade 0)
__device__ __forceinline__ void build_u8(const float4* __restrict__ W4,
                                         const float4* __restrict__ B4,
                                         int c8, const float xv[6], float u8[8]) {
    float4 b0 = B4[c8 * 2], b1 = B4[c8 * 2 + 1];
    u8[0] = b0.x; u8[1] = b0.y; u8[2] = b0.z; u8[3] = b0.w;
    u8[4] = b1.x; u8[5] = b1.y; u8[6] = b1.z; u8[7] = b1.w;
#pragma unroll
    for (int d = 0; d < 6; ++d) {
        float4 w0 = W4[d * 8 + c8 * 2], w1 = W4[d * 8 + c8 * 2 + 1];
        u8[0] = fmaf(xv[d], w0.x, u8[0]); u8[1] = fmaf(xv[d], w0.y, u8[1]);
        u8[2] = fmaf(xv[d], w0.z, u8[2]); u8[3] = fmaf(xv[d], w0.w, u8[3]);
        u8[4] = fmaf(xv[d], w1.x, u8[4]); u8[5] = fmaf(xv[d], w1.y, u8[5]);
        u8[6] = fmaf(xv[d], w1.z, u8[6]); u8[7] = fmaf(xv[d], w1.w, u8[7]);
    }
    if (c8 == 0) u8[0] += 1.0f;  // delta_r (unnormalized; scale cancels)
}

// np += (u8 chunk c8) (x) R  : np[i^j] += sgn(i,j)*u8[l]*R[j], i=c8*8+l
__device__ __forceinline__ void gp_chunk(float* __restrict__ np,
                                         const float u8[8],
                                         const float* __restrict__ R, int c8) {
#pragma unroll
    for (int l = 0; l < 8; ++l) {
        const int i = c8 * 8 + l;
#pragma unroll
        for (int j = 0; j < 32; ++j)
            np[i ^ j] = fmaf(SG.v[i][j] * u8[l], R[j], np[i ^ j]);
    }
}

// ---------------- pass 1: per-segment products -------------------
// thread u: h=u&15, bn=(u>>4)&255, s=u>>12. Raw product; normalize at store.
template <int SEGT>
__global__ __launch_bounds__(256, 2) void k_seg(
        const float* __restrict__ x, const float* __restrict__ W_in,
        const float* __restrict__ b_in, float* __restrict__ Q) {
    constexpr int L = 256 / SEGT;
    __shared__ float WL[16 * WIN_STRIDE];
    __shared__ float BL[16 * BIN_STRIDE];
    const int tid = threadIdx.x;
    for (int idx = tid; idx < 16 * WIN_STRIDE; idx += 256) {
        int h = idx / WIN_STRIDE, r = idx % WIN_STRIDE;
        if (r < 192) { int d = r >> 5, c = r & 31; WL[idx] = W_in[d * 512 + h * 32 + c]; }
    }
    for (int idx = tid; idx < 16 * BIN_STRIDE; idx += 256) {
        int h = idx / BIN_STRIDE, c = idx % BIN_STRIDE;
        if (c < 32) BL[idx] = b_in[h * 32 + c];
    }
    __syncthreads();

    const unsigned u = blockIdx.x * 256 + tid;
    const int h = u & 15, bn = (u >> 4) & 255, s = u >> 12;
    const int b = bn >> 4, n = bn & 15;
    const float4* W4 = (const float4*)(WL + h * WIN_STRIDE);
    const float4* B4 = (const float4*)(BL + h * BIN_STRIDE);

    float P[32];
    {   // step 0: P = u_0  (1 (x) u = u)
        const int t = s * L;
        const float2* xp = (const float2*)(x + ((b * 256 + t) * 16 + n) * 6);
        float2 x01 = xp[0], x23 = xp[1], x45 = xp[2];
        const float xv[6] = {x01.x, x01.y, x23.x, x23.y, x45.x, x45.y};
#pragma unroll
        for (int c8 = 0; c8 < 4; ++c8) build_u8(W4, B4, c8, xv, P + c8 * 8);
    }
    for (int i = 1; i < L; ++i) {
        const int t = s * L + i;
        const float2* xp = (const float2*)(x + ((b * 256 + t) * 16 + n) * 6);
        float2 x01 = xp[0], x23 = xp[1], x45 = xp[2];
        const float xv[6] = {x01.x, x01.y, x23.x, x23.y, x45.x, x45.y};
        float np[32];
#pragma unroll
        for (int k = 0; k < 32; ++k) np[k] = 0.0f;
#pragma unroll
        for (int c8 = 0; c8 < 4; ++c8) {
            float u8[8];
            build_u8(W4, B4, c8, xv, u8);
            gp_chunk(np, u8, P, c8);
        }
#pragma unroll
        for (int k = 0; k < 32; ++k) P[k] = np[k];  // raw; norm deferred
    }
    float rs = inv_norm(P);
    const int chain = bn * 16 + h;
    float4* qp = (float4*)(Q + (chain * SEGT + s) * 32);
#pragma unroll
    for (int r = 0; r < 8; ++r)
        qp[r] = make_float4(P[4 * r] * rs, P[4 * r + 1] * rs,
                            P[4 * r + 2] * rs, P[4 * r + 3] * rs);
}

// ---------------- pass 2: Kogge-Stone exclusive scan, in-wave ----------
template <int SEGT>
__global__ __launch_bounds__(256, 2) void k_scan(float* __restrict__ Q) {
    const unsigned u = blockIdx.x * 256 + threadIdx.x;
    const int s = u & (SEGT - 1);
    const unsigned chain = u / SEGT;

    float xr[32];
    {
        const float4* qp = (const float4*)(Q + (chain * SEGT + s) * 32);
#pragma unroll
        for (int r = 0; r < 8; ++r) {
            float4 v = qp[r];
            xr[4 * r] = v.x; xr[4 * r + 1] = v.y;
            xr[4 * r + 2] = v.z; xr[4 * r + 3] = v.w;
        }
    }
#pragma unroll
    for (int k = 1; k < SEGT; k <<= 1) {
        float pr[32];
#pragma unroll
        for (int j = 0; j < 32; ++j) pr[j] = __shfl_up(xr[j], k, SEGT);
        if (s >= k) {
            float np[32];
#pragma unroll
            for (int m = 0; m < 32; ++m) np[m] = 0.0f;
#pragma unroll
            for (int i = 0; i < 32; ++i)
#pragma unroll
                for (int j = 0; j < 32; ++j)
                    np[i ^ j] = fmaf(SG.v[i][j] * xr[i], pr[j], np[i ^ j]);
#pragma unroll
            for (int m = 0; m < 32; ++m) xr[m] = np[m];
        }
    }
    {   // single normalization of the inclusive prefix
        float rs = inv_norm(xr);
#pragma unroll
        for (int j = 0; j < 32; ++j) xr[j] *= rs;
    }
    // exclusive shift by one within the SEGT-group
    float er[32];
#pragma unroll
    for (int j = 0; j < 32; ++j) er[j] = __shfl_up(xr[j], 1, SEGT);
    if (s == 0) {
#pragma unroll
        for (int j = 0; j < 32; ++j) er[j] = 0.0f;
        er[0] = 1.0f;  // identity rotor
    }
    float4* qp = (float4*)(Q + (chain * SEGT + s) * 32);
#pragma unroll
    for (int r = 0; r < 8; ++r)
        qp[r] = make_float4(er[4 * r], er[4 * r + 1],
                            er[4 * r + 2], er[4 * r + 3]);
}

// ---------------- pass 3: apply interior + project + write output ----------
template <int SEGT>
__global__ __launch_bounds__(256, 2) void k_apply(
        const float* __restrict__ x, const float* __restrict__ W_in,
        const float* __restrict__ b_in, const float* __restrict__ W_out,
        const float* __restrict__ b_out, const float* __restrict__ Pre,
        float* __restrict__ out) {
    constexpr int L = 256 / SEGT;
    __shared__ float WL[16 * WIN_STRIDE];
    __shared__ float BL[16 * BIN_STRIDE];
    __shared__ float WO[16 * WIN_STRIDE];  // [h*196 + k*6 + d]
    const int tid = threadIdx.x;
    for (int idx = tid; idx < 16 * WIN_STRIDE; idx += 256) {
        int h = idx / WIN_STRIDE, r = idx % WIN_STRIDE;
        if (r < 192) {
            int d = r >> 5, c = r & 31;
            WL[idx] = W_in[d * 512 + h * 32 + c];
            WO[idx] = W_out[h * 192 + r];   // (h*32+k)*6+d == h*192 + (k*6+d)
        }
    }
    for (int idx = tid; idx < 16 * BIN_STRIDE; idx += 256) {
        int h = idx / BIN_STRIDE, c = idx % BIN_STRIDE;
        if (c < 32) BL[idx] = b_in[h * 32 + c];
    }
    __syncthreads();

    const unsigned u = blockIdx.x * 256 + tid;
    const int h = u & 15, bn = (u >> 4) & 255, s = u >> 12;
    const int b = bn >> 4, n = bn & 15;
    const int chain = bn * 16 + h;
    const float4* W4  = (const float4*)(WL + h * WIN_STRIDE);
    const float4* B4  = (const float4*)(BL + h * BIN_STRIDE);
    const float4* WO4 = (const float4*)(WO + h * WIN_STRIDE);

    float R[32];
    {
        const float4* pp = (const float4*)(Pre + (chain * SEGT + s) * 32);
#pragma unroll
        for (int r = 0; r < 8; ++r) {
            float4 v = pp[r];
            R[4 * r] = v.x; R[4 * r + 1] = v.y;
            R[4 * r + 2] = v.z; R[4 * r + 3] = v.w;
        }
    }
    float bo[6];
#pragma unroll
    for (int d = 0; d < 6; ++d) bo[d] = b_out[d];

    for (int i = 0; i < L; ++i) {
        const int t = s * L + i;
        const float2* xp = (const float2*)(x + ((b * 256 + t) * 16 + n) * 6);
        float2 x01 = xp[0], x23 = xp[1], x45 = xp[2];
        const float xv[6] = {x01.x, x01.y, x23.x, x23.y, x45.x, x45.y};
        float np[32];
#pragma unroll
        for (int k = 0; k < 32; ++k) np[k] = 0.0f;
#pragma unroll
        for (int c8 = 0; c8 < 4; ++c8) {
            float u8[8];
            build_u8(W4, B4, c8, xv, u8);
            gp_chunk(np, u8, R, c8);
        }
        // np = raw psi_t; fold normalization into pd
        float rs = inv_norm(np);

        float pd[6] = {0.f, 0.f, 0.f, 0.f, 0.f, 0.f};
#pragma unroll
        for (int c4 = 0; c4 < 48; ++c4) {
            float4 w = WO4[c4];
            pd[(4 * c4 + 0) % 6] = fmaf(np[(4 * c4 + 0) / 6], w.x, pd[(4 * c4 + 0) % 6]);
            pd[(4 * c4 + 1) % 6] = fmaf(np[(4 * c4 + 1) / 6], w.y, pd[(4 * c4 + 1) % 6]);
            pd[(4 * c4 + 2) % 6] = fmaf(np[(4 * c4 + 2) / 6], w.z, pd[(4 * c4 + 2) % 6]);
            pd[(4 * c4 + 3) % 6] = fmaf(np[(4 * c4 + 3) / 6], w.w, pd[(4 * c4 + 3) % 6]);
        }
#pragma unroll
        for (int k = 0; k < 32; ++k) R[k] = np[k];  // carry raw psi
#pragma unroll
        for (int d = 0; d < 6; ++d) pd[d] *= rs;
#pragma unroll
        for (int m = 1; m < 16; m <<= 1)
#pragma unroll
            for (int d = 0; d < 6; ++d)
                pd[d] += __shfl_xor(pd[d], m, 16);
        if ((tid & 15) == 0) {
            float* op = out + ((b * 256 + t) * 16 + n) * 6;
#pragma unroll
            for (int d = 0; d < 6; ++d) op[d] = xv[d] + bo[d] + pd[d];
        }
    }
}

extern "C" void kernel_launch(void* const* d_in, const int* in_sizes, int n_in,
                              void* d_out, int out_size, void* d_ws, size_t ws_size,
                              hipStream_t stream) {
    (void)in_sizes; (void)n_in; (void)out_size;
    const float* x     = (const float*)d_in[0];  // [16,256,16,6]
    const float* W_in  = (const float*)d_in[1];  // [6,512]
    const float* b_in  = (const float*)d_in[2];  // [512]
    const float* W_out = (const float*)d_in[3];  // [512,6]
    const float* b_out = (const float*)d_in[4];  // [6]
    float* out = (float*)d_out;                  // [16,256,16,6]
    float* Q   = (float*)d_ws;

    const size_t need32 = 4096UL * 32 * 32 * sizeof(float);  // 16 MB
    if (ws_size >= need32) {
        k_seg<32>  <<<512, 256, 0, stream>>>(x, W_in, b_in, Q);
        k_scan<32> <<<512, 256, 0, stream>>>(Q);
        k_apply<32><<<512, 256, 0, stream>>>(x, W_in, b_in, W_out, b_out, Q, out);
    } else {
        k_seg<16>  <<<256, 256, 0, stream>>>(x, W_in, b_in, Q);
        k_scan<16> <<<256, 256, 0, stream>>>(Q);
        k_apply<16><<<256, 256, 0, stream>>>(x, W_in, b_in, W_out, b_out, Q, out);
    }
}

// Round 5
// 203.539 us; speedup vs baseline: 1.8302x; 1.8302x over previous
//
#include <hip/hip_runtime.h>

// VersorRotorRNN: B=16, S=256, N=16, D=6, H=16, 32 blades (Cl(5,0)).
// Segmented parallel scan over S. normalize() is scale-invariant and the
// geometric product is bilinear+associative, so psi_t = N(dr_t (x) ... (x) dr_1)
// with dr unnormalized and all intermediate normalizations deferrable.
//
// R2+R4 lesson (engraved): NEVER set min-waves>=2 in __launch_bounds__ here.
//   (256,2) caps VGPR at 128 -> live set (~140+) spills -> 443MB/558MB scratch
//   traffic, 2.5x slowdown. Use (256,1); occupancy comes from grid size.
// R3 lesson: uu[32]+R[32]+np[32] live together -> VGPR 256 + mild spill.
// R5: streamed u-chunks (R4 structure) at natural register count.

#define EPS 1e-8f

// --- compile-time Cayley sign table: sgn(i,j) for C[i,j,i^j] ---
struct SgnTab { float v[32][32]; };
constexpr SgnTab make_sgn() {
    SgnTab t{};
    for (int i = 0; i < 32; ++i)
        for (int j = 0; j < 32; ++j) {
            int a = i >> 1, s = 0;
            while (a) {
                int x = a & j;
                while (x) { s += x & 1; x >>= 1; }
                a >>= 1;
            }
            t.v[i][j] = (s & 1) ? -1.0f : 1.0f;
        }
    return t;
}
__device__ constexpr SgnTab SG = make_sgn();

__device__ __forceinline__ float inv_norm(const float* v) {
    float s0 = 0.f, s1 = 0.f, s2 = 0.f, s3 = 0.f;
#pragma unroll
    for (int k = 0; k < 32; k += 4) {
        s0 = fmaf(v[k],     v[k],     s0);
        s1 = fmaf(v[k + 1], v[k + 1], s1);
        s2 = fmaf(v[k + 2], v[k + 2], s2);
        s3 = fmaf(v[k + 3], v[k + 3], s3);
    }
    return rsqrtf((s0 + s1) + (s2 + s3) + EPS);
}

// LDS layouts (per-h, b128-friendly):
//   WIN: stride 196 floats/h: [h*196 + d*32 + c]   (196%32==4 -> rows h,h+8
//   BIN: stride  36 floats/h: [h*36 + c]            share banks = 2-way = free;
//   WOU: stride 196 floats/h: [h*196 + k*6 + d]     196%4==0 -> 16B aligned)
#define WIN_STRIDE 196
#define BIN_STRIDE 36

// build u8 = chunk c8 (8 blades) of  b_in[h] + x . W_in[:,h*32+...]  (+1 on blade 0)
__device__ __forceinline__ void build_u8(const float4* __restrict__ W4,
                                         const float4* __restrict__ B4,
                                         int c8, const float xv[6], float u8[8]) {
    float4 b0 = B4[c8 * 2], b1 = B4[c8 * 2 + 1];
    u8[0] = b0.x; u8[1] = b0.y; u8[2] = b0.z; u8[3] = b0.w;
    u8[4] = b1.x; u8[5] = b1.y; u8[6] = b1.z; u8[7] = b1.w;
#pragma unroll
    for (int d = 0; d < 6; ++d) {
        float4 w0 = W4[d * 8 + c8 * 2], w1 = W4[d * 8 + c8 * 2 + 1];
        u8[0] = fmaf(xv[d], w0.x, u8[0]); u8[1] = fmaf(xv[d], w0.y, u8[1]);
        u8[2] = fmaf(xv[d], w0.z, u8[2]); u8[3] = fmaf(xv[d], w0.w, u8[3]);
        u8[4] = fmaf(xv[d], w1.x, u8[4]); u8[5] = fmaf(xv[d], w1.y, u8[5]);
        u8[6] = fmaf(xv[d], w1.z, u8[6]); u8[7] = fmaf(xv[d], w1.w, u8[7]);
    }
    if (c8 == 0) u8[0] += 1.0f;  // delta_r (unnormalized; scale cancels)
}

// np += (u8 chunk c8) (x) R  : np[i^j] += sgn(i,j)*u8[l]*R[j], i=c8*8+l
__device__ __forceinline__ void gp_chunk(float* __restrict__ np,
                                         const float u8[8],
                                         const float* __restrict__ R, int c8) {
#pragma unroll
    for (int l = 0; l < 8; ++l) {
        const int i = c8 * 8 + l;
#pragma unroll
        for (int j = 0; j < 32; ++j)
            np[i ^ j] = fmaf(SG.v[i][j] * u8[l], R[j], np[i ^ j]);
    }
}

// ---------------- pass 1: per-segment products -------------------
// thread u: h=u&15, bn=(u>>4)&255, s=u>>12. Raw product; normalize at store.
template <int SEGT>
__global__ __launch_bounds__(256, 1) void k_seg(
        const float* __restrict__ x, const float* __restrict__ W_in,
        const float* __restrict__ b_in, float* __restrict__ Q) {
    constexpr int L = 256 / SEGT;
    __shared__ float WL[16 * WIN_STRIDE];
    __shared__ float BL[16 * BIN_STRIDE];
    const int tid = threadIdx.x;
    for (int idx = tid; idx < 16 * WIN_STRIDE; idx += 256) {
        int h = idx / WIN_STRIDE, r = idx % WIN_STRIDE;
        if (r < 192) { int d = r >> 5, c = r & 31; WL[idx] = W_in[d * 512 + h * 32 + c]; }
    }
    for (int idx = tid; idx < 16 * BIN_STRIDE; idx += 256) {
        int h = idx / BIN_STRIDE, c = idx % BIN_STRIDE;
        if (c < 32) BL[idx] = b_in[h * 32 + c];
    }
    __syncthreads();

    const unsigned u = blockIdx.x * 256 + tid;
    const int h = u & 15, bn = (u >> 4) & 255, s = u >> 12;
    const int b = bn >> 4, n = bn & 15;
    const float4* W4 = (const float4*)(WL + h * WIN_STRIDE);
    const float4* B4 = (const float4*)(BL + h * BIN_STRIDE);

    float P[32];
    {   // step 0: P = u_0  (1 (x) u = u)
        const int t = s * L;
        const float2* xp = (const float2*)(x + ((b * 256 + t) * 16 + n) * 6);
        float2 x01 = xp[0], x23 = xp[1], x45 = xp[2];
        const float xv[6] = {x01.x, x01.y, x23.x, x23.y, x45.x, x45.y};
#pragma unroll
        for (int c8 = 0; c8 < 4; ++c8) build_u8(W4, B4, c8, xv, P + c8 * 8);
    }
    for (int i = 1; i < L; ++i) {
        const int t = s * L + i;
        const float2* xp = (const float2*)(x + ((b * 256 + t) * 16 + n) * 6);
        float2 x01 = xp[0], x23 = xp[1], x45 = xp[2];
        const float xv[6] = {x01.x, x01.y, x23.x, x23.y, x45.x, x45.y};
        float np[32];
#pragma unroll
        for (int k = 0; k < 32; ++k) np[k] = 0.0f;
#pragma unroll
        for (int c8 = 0; c8 < 4; ++c8) {
            float u8[8];
            build_u8(W4, B4, c8, xv, u8);
            gp_chunk(np, u8, P, c8);
        }
#pragma unroll
        for (int k = 0; k < 32; ++k) P[k] = np[k];  // raw; norm deferred
    }
    float rs = inv_norm(P);
    const int chain = bn * 16 + h;
    float4* qp = (float4*)(Q + (chain * SEGT + s) * 32);
#pragma unroll
    for (int r = 0; r < 8; ++r)
        qp[r] = make_float4(P[4 * r] * rs, P[4 * r + 1] * rs,
                            P[4 * r + 2] * rs, P[4 * r + 3] * rs);
}

// ---------------- pass 2: Kogge-Stone exclusive scan, in-wave ----------
template <int SEGT>
__global__ __launch_bounds__(256, 1) void k_scan(float* __restrict__ Q) {
    const unsigned u = blockIdx.x * 256 + threadIdx.x;
    const int s = u & (SEGT - 1);
    const unsigned chain = u / SEGT;

    float xr[32];
    {
        const float4* qp = (const float4*)(Q + (chain * SEGT + s) * 32);
#pragma unroll
        for (int r = 0; r < 8; ++r) {
            float4 v = qp[r];
            xr[4 * r] = v.x; xr[4 * r + 1] = v.y;
            xr[4 * r + 2] = v.z; xr[4 * r + 3] = v.w;
        }
    }
#pragma unroll
    for (int k = 1; k < SEGT; k <<= 1) {
        float pr[32];
#pragma unroll
        for (int j = 0; j < 32; ++j) pr[j] = __shfl_up(xr[j], k, SEGT);
        if (s >= k) {
            float np[32];
#pragma unroll
            for (int m = 0; m < 32; ++m) np[m] = 0.0f;
#pragma unroll
            for (int i = 0; i < 32; ++i)
#pragma unroll
                for (int j = 0; j < 32; ++j)
                    np[i ^ j] = fmaf(SG.v[i][j] * xr[i], pr[j], np[i ^ j]);
#pragma unroll
            for (int m = 0; m < 32; ++m) xr[m] = np[m];
        }
    }
    {   // single normalization of the inclusive prefix
        float rs = inv_norm(xr);
#pragma unroll
        for (int j = 0; j < 32; ++j) xr[j] *= rs;
    }
    // exclusive shift by one within the SEGT-group
    float er[32];
#pragma unroll
    for (int j = 0; j < 32; ++j) er[j] = __shfl_up(xr[j], 1, SEGT);
    if (s == 0) {
#pragma unroll
        for (int j = 0; j < 32; ++j) er[j] = 0.0f;
        er[0] = 1.0f;  // identity rotor
    }
    float4* qp = (float4*)(Q + (chain * SEGT + s) * 32);
#pragma unroll
    for (int r = 0; r < 8; ++r)
        qp[r] = make_float4(er[4 * r], er[4 * r + 1],
                            er[4 * r + 2], er[4 * r + 3]);
}

// ---------------- pass 3: apply interior + project + write output ----------
template <int SEGT>
__global__ __launch_bounds__(256, 1) void k_apply(
        const float* __restrict__ x, const float* __restrict__ W_in,
        const float* __restrict__ b_in, const float* __restrict__ W_out,
        const float* __restrict__ b_out, const float* __restrict__ Pre,
        float* __restrict__ out) {
    constexpr int L = 256 / SEGT;
    __shared__ float WL[16 * WIN_STRIDE];
    __shared__ float BL[16 * BIN_STRIDE];
    __shared__ float WO[16 * WIN_STRIDE];  // [h*196 + k*6 + d]
    const int tid = threadIdx.x;
    for (int idx = tid; idx < 16 * WIN_STRIDE; idx += 256) {
        int h = idx / WIN_STRIDE, r = idx % WIN_STRIDE;
        if (r < 192) {
            int d = r >> 5, c = r & 31;
            WL[idx] = W_in[d * 512 + h * 32 + c];
            WO[idx] = W_out[h * 192 + r];   // (h*32+k)*6+d == h*192 + (k*6+d)
        }
    }
    for (int idx = tid; idx < 16 * BIN_STRIDE; idx += 256) {
        int h = idx / BIN_STRIDE, c = idx % BIN_STRIDE;
        if (c < 32) BL[idx] = b_in[h * 32 + c];
    }
    __syncthreads();

    const unsigned u = blockIdx.x * 256 + tid;
    const int h = u & 15, bn = (u >> 4) & 255, s = u >> 12;
    const int b = bn >> 4, n = bn & 15;
    const int chain = bn * 16 + h;
    const float4* W4  = (const float4*)(WL + h * WIN_STRIDE);
    const float4* B4  = (const float4*)(BL + h * BIN_STRIDE);
    const float4* WO4 = (const float4*)(WO + h * WIN_STRIDE);

    float R[32];
    {
        const float4* pp = (const float4*)(Pre + (chain * SEGT + s) * 32);
#pragma unroll
        for (int r = 0; r < 8; ++r) {
            float4 v = pp[r];
            R[4 * r] = v.x; R[4 * r + 1] = v.y;
            R[4 * r + 2] = v.z; R[4 * r + 3] = v.w;
        }
    }
    float bo[6];
#pragma unroll
    for (int d = 0; d < 6; ++d) bo[d] = b_out[d];

    for (int i = 0; i < L; ++i) {
        const int t = s * L + i;
        const float2* xp = (const float2*)(x + ((b * 256 + t) * 16 + n) * 6);
        float2 x01 = xp[0], x23 = xp[1], x45 = xp[2];
        const float xv[6] = {x01.x, x01.y, x23.x, x23.y, x45.x, x45.y};
        float np[32];
#pragma unroll
        for (int k = 0; k < 32; ++k) np[k] = 0.0f;
#pragma unroll
        for (int c8 = 0; c8 < 4; ++c8) {
            float u8[8];
            build_u8(W4, B4, c8, xv, u8);
            gp_chunk(np, u8, R, c8);
        }
        // np = raw psi_t; fold normalization into pd
        float rs = inv_norm(np);

        float pd[6] = {0.f, 0.f, 0.f, 0.f, 0.f, 0.f};
#pragma unroll
        for (int c4 = 0; c4 < 48; ++c4) {
            float4 w = WO4[c4];
            pd[(4 * c4 + 0) % 6] = fmaf(np[(4 * c4 + 0) / 6], w.x, pd[(4 * c4 + 0) % 6]);
            pd[(4 * c4 + 1) % 6] = fmaf(np[(4 * c4 + 1) / 6], w.y, pd[(4 * c4 + 1) % 6]);
            pd[(4 * c4 + 2) % 6] = fmaf(np[(4 * c4 + 2) / 6], w.z, pd[(4 * c4 + 2) % 6]);
            pd[(4 * c4 + 3) % 6] = fmaf(np[(4 * c4 + 3) / 6], w.w, pd[(4 * c4 + 3) % 6]);
        }
#pragma unroll
        for (int k = 0; k < 32; ++k) R[k] = np[k];  // carry raw psi
#pragma unroll
        for (int d = 0; d < 6; ++d) pd[d] *= rs;
#pragma unroll
        for (int m = 1; m < 16; m <<= 1)
#pragma unroll
            for (int d = 0; d < 6; ++d)
                pd[d] += __shfl_xor(pd[d], m, 16);
        if ((tid & 15) == 0) {
            float* op = out + ((b * 256 + t) * 16 + n) * 6;
#pragma unroll
            for (int d = 0; d < 6; ++d) op[d] = xv[d] + bo[d] + pd[d];
        }
    }
}

extern "C" void kernel_launch(void* const* d_in, const int* in_sizes, int n_in,
                              void* d_out, int out_size, void* d_ws, size_t ws_size,
                              hipStream_t stream) {
    (void)in_sizes; (void)n_in; (void)out_size;
    const float* x     = (const float*)d_in[0];  // [16,256,16,6]
    const float* W_in  = (const float*)d_in[1];  // [6,512]
    const float* b_in  = (const float*)d_in[2];  // [512]
    const float* W_out = (const float*)d_in[3];  // [512,6]
    const float* b_out = (const float*)d_in[4];  // [6]
    float* out = (float*)d_out;                  // [16,256,16,6]
    float* Q   = (float*)d_ws;

    const size_t need32 = 4096UL * 32 * 32 * sizeof(float);  // 16 MB
    if (ws_size >= need32) {
        k_seg<32>  <<<512, 256, 0, stream>>>(x, W_in, b_in, Q);
        k_scan<32> <<<512, 256, 0, stream>>>(Q);
        k_apply<32><<<512, 256, 0, stream>>>(x, W_in, b_in, W_out, b_out, Q, out);
    } else {
        k_seg<16>  <<<256, 256, 0, stream>>>(x, W_in, b_in, Q);
        k_scan<16> <<<256, 256, 0, stream>>>(Q);
        k_apply<16><<<256, 256, 0, stream>>>(x, W_in, b_in, W_out, b_out, Q, out);
    }
}

// Round 6
// 176.641 us; speedup vs baseline: 2.1089x; 1.1523x over previous
//
#include <hip/hip_runtime.h>

// VersorRotorRNN: B=16, S=256, N=16, D=6, H=16, 32 blades (Cl(5,0)).
// Segmented parallel scan over S (SEGT=32, L=8). normalize() is
// scale-invariant; GP is bilinear+associative -> defer normalization.
//
// R2+R4 lesson: NEVER set min-waves>=2 (VGPR cap 128 -> spill).
// R5 lesson: per-thread LDS weight reads saturate the CU LDS pipe
//   (852 KB/step/CU vs 85 B/cyc => 10k cyc/step vs 5.8k VALU cyc).
// R6: wave-per-h mapping -> weights are wave-uniform (scalar loads),
//   LDS eliminated. Cross-wave h-reduction moved to a small 4th kernel.

#define EPS 1e-8f

struct SgnTab { float v[32][32]; };
constexpr SgnTab make_sgn() {
    SgnTab t{};
    for (int i = 0; i < 32; ++i)
        for (int j = 0; j < 32; ++j) {
            int a = i >> 1, s = 0;
            while (a) {
                int x = a & j;
                while (x) { s += x & 1; x >>= 1; }
                a >>= 1;
            }
            t.v[i][j] = (s & 1) ? -1.0f : 1.0f;
        }
    return t;
}
__device__ constexpr SgnTab SG = make_sgn();

__device__ __forceinline__ float inv_norm(const float* v) {
    float s0 = 0.f, s1 = 0.f, s2 = 0.f, s3 = 0.f;
#pragma unroll
    for (int k = 0; k < 32; k += 4) {
        s0 = fmaf(v[k],     v[k],     s0);
        s1 = fmaf(v[k + 1], v[k + 1], s1);
        s2 = fmaf(v[k + 2], v[k + 2], s2);
        s3 = fmaf(v[k + 3], v[k + 3], s3);
    }
    return rsqrtf((s0 + s1) + (s2 + s3) + EPS);
}

// np += (u8 chunk c8) (x) R : np[i^j] += sgn(i,j)*u8[l]*R[j], i=c8*8+l
__device__ __forceinline__ void gp_chunk(float* __restrict__ np,
                                         const float u8[8],
                                         const float* __restrict__ R, int c8) {
#pragma unroll
    for (int l = 0; l < 8; ++l) {
        const int i = c8 * 8 + l;
#pragma unroll
        for (int j = 0; j < 32; ++j)
            np[i ^ j] = fmaf(SG.v[i][j] * u8[l], R[j], np[i ^ j]);
    }
}

// ======================= NEW wave-per-h path =======================
// Wave wid (0..2047): h = wid&15, g = (wid>>4)&3, s = wid>>6.
// Lane = bn-chain within group g (bn = g*64+lane, bn = b*16+n).
// Weights indexed by h only -> wave-uniform -> scalar/K$ loads, no LDS.

// u8 = chunk c8 of  b_in[h] + x.W_in[:, h*32+..]  (+1 on blade 0)
__device__ __forceinline__ void build_u8_s(const float* __restrict__ Wh,
                                           const float* __restrict__ Bh,
                                           int c8, const float xv[6], float u8[8]) {
#pragma unroll
    for (int l = 0; l < 8; ++l) u8[l] = Bh[c8 * 8 + l];
#pragma unroll
    for (int d = 0; d < 6; ++d)
#pragma unroll
        for (int l = 0; l < 8; ++l)
            u8[l] = fmaf(xv[d], Wh[d * 512 + c8 * 8 + l], u8[l]);
    if (c8 == 0) u8[0] += 1.0f;
}

// Q layout: [s][h][bn][32]  (coalesced for k_seg2 store / k_apply2 load)
__global__ __launch_bounds__(256, 1) void k_seg2(
        const float* __restrict__ x, const float* __restrict__ W_in,
        const float* __restrict__ b_in, float* __restrict__ Q) {
    const int lane = threadIdx.x & 63;
    const int wid = __builtin_amdgcn_readfirstlane(
        (int)(blockIdx.x * 4 + (threadIdx.x >> 6)));
    const int h = wid & 15, g = (wid >> 4) & 3, s = wid >> 6;
    const int bn = g * 64 + lane, b = bn >> 4, n = bn & 15;
    const float* __restrict__ Wh = W_in + h * 32;  // [d*512 + c]
    const float* __restrict__ Bh = b_in + h * 32;

    float P[32];
    {   // step 0: P = u_0
        const int t = s * 8;
        const float2* xp = (const float2*)(x + ((b * 256 + t) * 16 + n) * 6);
        float2 x01 = xp[0], x23 = xp[1], x45 = xp[2];
        const float xv[6] = {x01.x, x01.y, x23.x, x23.y, x45.x, x45.y};
#pragma unroll
        for (int c8 = 0; c8 < 4; ++c8) build_u8_s(Wh, Bh, c8, xv, P + c8 * 8);
    }
    for (int i = 1; i < 8; ++i) {
        const int t = s * 8 + i;
        const float2* xp = (const float2*)(x + ((b * 256 + t) * 16 + n) * 6);
        float2 x01 = xp[0], x23 = xp[1], x45 = xp[2];
        const float xv[6] = {x01.x, x01.y, x23.x, x23.y, x45.x, x45.y};
        float np[32];
#pragma unroll
        for (int k = 0; k < 32; ++k) np[k] = 0.0f;
#pragma unroll
        for (int c8 = 0; c8 < 4; ++c8) {
            float u8[8];
            build_u8_s(Wh, Bh, c8, xv, u8);
            gp_chunk(np, u8, P, c8);
        }
#pragma unroll
        for (int k = 0; k < 32; ++k) P[k] = np[k];  // raw; norm deferred
    }
    float rs = inv_norm(P);
    float4* qp = (float4*)(Q + (((s * 16 + h) * 256) + bn) * 32);
#pragma unroll
    for (int r = 0; r < 8; ++r)
        qp[r] = make_float4(P[4 * r] * rs, P[4 * r + 1] * rs,
                            P[4 * r + 2] * rs, P[4 * r + 3] * rs);
}

// Kogge-Stone exclusive scan over s (32 lanes per chain, 2 chains/wave)
__global__ __launch_bounds__(256, 1) void k_scan2(float* __restrict__ Q) {
    const unsigned u = blockIdx.x * 256 + threadIdx.x;
    const int s = u & 31;
    const unsigned chain = u >> 5;          // bn*16 + h
    const int h = chain & 15, bn = chain >> 4;
    float* base = Q + (((s * 16 + h) * 256) + bn) * 32;

    float xr[32];
    {
        const float4* qp = (const float4*)base;
#pragma unroll
        for (int r = 0; r < 8; ++r) {
            float4 v = qp[r];
            xr[4 * r] = v.x; xr[4 * r + 1] = v.y;
            xr[4 * r + 2] = v.z; xr[4 * r + 3] = v.w;
        }
    }
#pragma unroll
    for (int k = 1; k < 32; k <<= 1) {
        float pr[32];
#pragma unroll
        for (int j = 0; j < 32; ++j) pr[j] = __shfl_up(xr[j], k, 32);
        if (s >= k) {
            float np[32];
#pragma unroll
            for (int m = 0; m < 32; ++m) np[m] = 0.0f;
#pragma unroll
            for (int i = 0; i < 32; ++i)
#pragma unroll
                for (int j = 0; j < 32; ++j)
                    np[i ^ j] = fmaf(SG.v[i][j] * xr[i], pr[j], np[i ^ j]);
#pragma unroll
            for (int m = 0; m < 32; ++m) xr[m] = np[m];
        }
    }
    {
        float rs = inv_norm(xr);
#pragma unroll
        for (int j = 0; j < 32; ++j) xr[j] *= rs;
    }
    float er[32];
#pragma unroll
    for (int j = 0; j < 32; ++j) er[j] = __shfl_up(xr[j], 1, 32);
    if (s == 0) {
#pragma unroll
        for (int j = 0; j < 32; ++j) er[j] = 0.0f;
        er[0] = 1.0f;
    }
    float4* qp = (float4*)base;
#pragma unroll
    for (int r = 0; r < 8; ++r)
        qp[r] = make_float4(er[4 * r], er[4 * r + 1],
                            er[4 * r + 2], er[4 * r + 3]);
}

// apply interior + project; write per-(t,h,bn) partials to WS2[t][h][bn][6]
__global__ __launch_bounds__(256, 1) void k_apply2(
        const float* __restrict__ x, const float* __restrict__ W_in,
        const float* __restrict__ b_in, const float* __restrict__ W_out,
        const float* __restrict__ Pre, float* __restrict__ WS2) {
    const int lane = threadIdx.x & 63;
    const int wid = __builtin_amdgcn_readfirstlane(
        (int)(blockIdx.x * 4 + (threadIdx.x >> 6)));
    const int h = wid & 15, g = (wid >> 4) & 3, s = wid >> 6;
    const int bn = g * 64 + lane, b = bn >> 4, n = bn & 15;
    const float* __restrict__ Wh = W_in + h * 32;
    const float* __restrict__ Bh = b_in + h * 32;
    const float* __restrict__ Oh = W_out + h * 192;  // [k*6 + d]

    float R[32];
    {
        const float4* pp = (const float4*)(Pre + (((s * 16 + h) * 256) + bn) * 32);
#pragma unroll
        for (int r = 0; r < 8; ++r) {
            float4 v = pp[r];
            R[4 * r] = v.x; R[4 * r + 1] = v.y;
            R[4 * r + 2] = v.z; R[4 * r + 3] = v.w;
        }
    }
    for (int i = 0; i < 8; ++i) {
        const int t = s * 8 + i;
        const float2* xp = (const float2*)(x + ((b * 256 + t) * 16 + n) * 6);
        float2 x01 = xp[0], x23 = xp[1], x45 = xp[2];
        const float xv[6] = {x01.x, x01.y, x23.x, x23.y, x45.x, x45.y};
        float np[32];
#pragma unroll
        for (int k = 0; k < 32; ++k) np[k] = 0.0f;
#pragma unroll
        for (int c8 = 0; c8 < 4; ++c8) {
            float u8[8];
            build_u8_s(Wh, Bh, c8, xv, u8);
            gp_chunk(np, u8, R, c8);
        }
        float rs = inv_norm(np);     // fold normalization into pd
        float pd[6] = {0.f, 0.f, 0.f, 0.f, 0.f, 0.f};
#pragma unroll
        for (int k = 0; k < 32; ++k)
#pragma unroll
            for (int d = 0; d < 6; ++d)
                pd[d] = fmaf(np[k], Oh[k * 6 + d], pd[d]);
#pragma unroll
        for (int k = 0; k < 32; ++k) R[k] = np[k];  // carry raw psi
        float2* wp = (float2*)(WS2 + (((t * 16 + h) * 256) + bn) * 6);
        wp[0] = make_float2(pd[0] * rs, pd[1] * rs);
        wp[1] = make_float2(pd[2] * rs, pd[3] * rs);
        wp[2] = make_float2(pd[4] * rs, pd[5] * rs);
    }
}

// out[o] = x[o] + b_out[d] + sum_h WS2[t][h][bn][d]   (o = ((b*256+t)*16+n)*6+d)
__global__ __launch_bounds__(256, 1) void k_reduce(
        const float* __restrict__ x, const float* __restrict__ b_out,
        const float* __restrict__ WS2, float* __restrict__ out) {
    const int o = blockIdx.x * 256 + threadIdx.x;  // 393216 total
    const int d = o % 6;
    const int r = o / 6;
    const int n = r & 15;
    const int r2 = r >> 4;
    const int t = r2 & 255;
    const int b = r2 >> 8;
    const int bn = b * 16 + n;
    float acc = x[o] + b_out[d];
#pragma unroll
    for (int h = 0; h < 16; ++h)
        acc += WS2[(((t * 16 + h) * 256) + bn) * 6 + d];
    out[o] = acc;
}

// ======================= Fallback (R5) path =======================
#define WIN_STRIDE 196
#define BIN_STRIDE 36

__device__ __forceinline__ void build_u8(const float4* __restrict__ W4,
                                         const float4* __restrict__ B4,
                                         int c8, const float xv[6], float u8[8]) {
    float4 b0 = B4[c8 * 2], b1 = B4[c8 * 2 + 1];
    u8[0] = b0.x; u8[1] = b0.y; u8[2] = b0.z; u8[3] = b0.w;
    u8[4] = b1.x; u8[5] = b1.y; u8[6] = b1.z; u8[7] = b1.w;
#pragma unroll
    for (int d = 0; d < 6; ++d) {
        float4 w0 = W4[d * 8 + c8 * 2], w1 = W4[d * 8 + c8 * 2 + 1];
        u8[0] = fmaf(xv[d], w0.x, u8[0]); u8[1] = fmaf(xv[d], w0.y, u8[1]);
        u8[2] = fmaf(xv[d], w0.z, u8[2]); u8[3] = fmaf(xv[d], w0.w, u8[3]);
        u8[4] = fmaf(xv[d], w1.x, u8[4]); u8[5] = fmaf(xv[d], w1.y, u8[5]);
        u8[6] = fmaf(xv[d], w1.z, u8[6]); u8[7] = fmaf(xv[d], w1.w, u8[7]);
    }
    if (c8 == 0) u8[0] += 1.0f;
}

template <int SEGT>
__global__ __launch_bounds__(256, 1) void k_seg_fb(
        const float* __restrict__ x, const float* __restrict__ W_in,
        const float* __restrict__ b_in, float* __restrict__ Q) {
    constexpr int L = 256 / SEGT;
    __shared__ float WL[16 * WIN_STRIDE];
    __shared__ float BL[16 * BIN_STRIDE];
    const int tid = threadIdx.x;
    for (int idx = tid; idx < 16 * WIN_STRIDE; idx += 256) {
        int h = idx / WIN_STRIDE, r = idx % WIN_STRIDE;
        if (r < 192) { int d = r >> 5, c = r & 31; WL[idx] = W_in[d * 512 + h * 32 + c]; }
    }
    for (int idx = tid; idx < 16 * BIN_STRIDE; idx += 256) {
        int h = idx / BIN_STRIDE, c = idx % BIN_STRIDE;
        if (c < 32) BL[idx] = b_in[h * 32 + c];
    }
    __syncthreads();
    const unsigned u = blockIdx.x * 256 + tid;
    const int h = u & 15, bn = (u >> 4) & 255, s = u >> 12;
    const int b = bn >> 4, n = bn & 15;
    const float4* W4 = (const float4*)(WL + h * WIN_STRIDE);
    const float4* B4 = (const float4*)(BL + h * BIN_STRIDE);
    float P[32];
    {
        const int t = s * L;
        const float2* xp = (const float2*)(x + ((b * 256 + t) * 16 + n) * 6);
        float2 x01 = xp[0], x23 = xp[1], x45 = xp[2];
        const float xv[6] = {x01.x, x01.y, x23.x, x23.y, x45.x, x45.y};
#pragma unroll
        for (int c8 = 0; c8 < 4; ++c8) build_u8(W4, B4, c8, xv, P + c8 * 8);
    }
    for (int i = 1; i < L; ++i) {
        const int t = s * L + i;
        const float2* xp = (const float2*)(x + ((b * 256 + t) * 16 + n) * 6);
        float2 x01 = xp[0], x23 = xp[1], x45 = xp[2];
        const float xv[6] = {x01.x, x01.y, x23.x, x23.y, x45.x, x45.y};
        float np[32];
#pragma unroll
        for (int k = 0; k < 32; ++k) np[k] = 0.0f;
#pragma unroll
        for (int c8 = 0; c8 < 4; ++c8) {
            float u8[8];
            build_u8(W4, B4, c8, xv, u8);
            gp_chunk(np, u8, P, c8);
        }
#pragma unroll
        for (int k = 0; k < 32; ++k) P[k] = np[k];
    }
    float rs = inv_norm(P);
    const int chain = bn * 16 + h;
    float4* qp = (float4*)(Q + (chain * SEGT + s) * 32);
#pragma unroll
    for (int r = 0; r < 8; ++r)
        qp[r] = make_float4(P[4 * r] * rs, P[4 * r + 1] * rs,
                            P[4 * r + 2] * rs, P[4 * r + 3] * rs);
}

template <int SEGT>
__global__ __launch_bounds__(256, 1) void k_scan_fb(float* __restrict__ Q) {
    const unsigned u = blockIdx.x * 256 + threadIdx.x;
    const int s = u & (SEGT - 1);
    const unsigned chain = u / SEGT;
    float xr[32];
    {
        const float4* qp = (const float4*)(Q + (chain * SEGT + s) * 32);
#pragma unroll
        for (int r = 0; r < 8; ++r) {
            float4 v = qp[r];
            xr[4 * r] = v.x; xr[4 * r + 1] = v.y;
            xr[4 * r + 2] = v.z; xr[4 * r + 3] = v.w;
        }
    }
#pragma unroll
    for (int k = 1; k < SEGT; k <<= 1) {
        float pr[32];
#pragma unroll
        for (int j = 0; j < 32; ++j) pr[j] = __shfl_up(xr[j], k, SEGT);
        if (s >= k) {
            float np[32];
#pragma unroll
            for (int m = 0; m < 32; ++m) np[m] = 0.0f;
#pragma unroll
            for (int i = 0; i < 32; ++i)
#pragma unroll
                for (int j = 0; j < 32; ++j)
                    np[i ^ j] = fmaf(SG.v[i][j] * xr[i], pr[j], np[i ^ j]);
#pragma unroll
            for (int m = 0; m < 32; ++m) xr[m] = np[m];
        }
    }
    {
        float rs = inv_norm(xr);
#pragma unroll
        for (int j = 0; j < 32; ++j) xr[j] *= rs;
    }
    float er[32];
#pragma unroll
    for (int j = 0; j < 32; ++j) er[j] = __shfl_up(xr[j], 1, SEGT);
    if (s == 0) {
#pragma unroll
        for (int j = 0; j < 32; ++j) er[j] = 0.0f;
        er[0] = 1.0f;
    }
    float4* qp = (float4*)(Q + (chain * SEGT + s) * 32);
#pragma unroll
    for (int r = 0; r < 8; ++r)
        qp[r] = make_float4(er[4 * r], er[4 * r + 1],
                            er[4 * r + 2], er[4 * r + 3]);
}

template <int SEGT>
__global__ __launch_bounds__(256, 1) void k_apply_fb(
        const float* __restrict__ x, const float* __restrict__ W_in,
        const float* __restrict__ b_in, const float* __restrict__ W_out,
        const float* __restrict__ b_out, const float* __restrict__ Pre,
        float* __restrict__ out) {
    constexpr int L = 256 / SEGT;
    __shared__ float WL[16 * WIN_STRIDE];
    __shared__ float BL[16 * BIN_STRIDE];
    __shared__ float WO[16 * WIN_STRIDE];
    const int tid = threadIdx.x;
    for (int idx = tid; idx < 16 * WIN_STRIDE; idx += 256) {
        int h = idx / WIN_STRIDE, r = idx % WIN_STRIDE;
        if (r < 192) {
            int d = r >> 5, c = r & 31;
            WL[idx] = W_in[d * 512 + h * 32 + c];
            WO[idx] = W_out[h * 192 + r];
        }
    }
    for (int idx = tid; idx < 16 * BIN_STRIDE; idx += 256) {
        int h = idx / BIN_STRIDE, c = idx % BIN_STRIDE;
        if (c < 32) BL[idx] = b_in[h * 32 + c];
    }
    __syncthreads();
    const unsigned u = blockIdx.x * 256 + tid;
    const int h = u & 15, bn = (u >> 4) & 255, s = u >> 12;
    const int b = bn >> 4, n = bn & 15;
    const int chain = bn * 16 + h;
    const float4* W4  = (const float4*)(WL + h * WIN_STRIDE);
    const float4* B4  = (const float4*)(BL + h * BIN_STRIDE);
    const float4* WO4 = (const float4*)(WO + h * WIN_STRIDE);
    float R[32];
    {
        const float4* pp = (const float4*)(Pre + (chain * SEGT + s) * 32);
#pragma unroll
        for (int r = 0; r < 8; ++r) {
            float4 v = pp[r];
            R[4 * r] = v.x; R[4 * r + 1] = v.y;
            R[4 * r + 2] = v.z; R[4 * r + 3] = v.w;
        }
    }
    float bo[6];
#pragma unroll
    for (int d = 0; d < 6; ++d) bo[d] = b_out[d];
    for (int i = 0; i < L; ++i) {
        const int t = s * L + i;
        const float2* xp = (const float2*)(x + ((b * 256 + t) * 16 + n) * 6);
        float2 x01 = xp[0], x23 = xp[1], x45 = xp[2];
        const float xv[6] = {x01.x, x01.y, x23.x, x23.y, x45.x, x45.y};
        float np[32];
#pragma unroll
        for (int k = 0; k < 32; ++k) np[k] = 0.0f;
#pragma unroll
        for (int c8 = 0; c8 < 4; ++c8) {
            float u8[8];
            build_u8(W4, B4, c8, xv, u8);
            gp_chunk(np, u8, R, c8);
        }
        float rs = inv_norm(np);
        float pd[6] = {0.f, 0.f, 0.f, 0.f, 0.f, 0.f};
#pragma unroll
        for (int c4 = 0; c4 < 48; ++c4) {
            float4 w = WO4[c4];
            pd[(4 * c4 + 0) % 6] = fmaf(np[(4 * c4 + 0) / 6], w.x, pd[(4 * c4 + 0) % 6]);
            pd[(4 * c4 + 1) % 6] = fmaf(np[(4 * c4 + 1) / 6], w.y, pd[(4 * c4 + 1) % 6]);
            pd[(4 * c4 + 2) % 6] = fmaf(np[(4 * c4 + 2) / 6], w.z, pd[(4 * c4 + 2) % 6]);
            pd[(4 * c4 + 3) % 6] = fmaf(np[(4 * c4 + 3) / 6], w.w, pd[(4 * c4 + 3) % 6]);
        }
#pragma unroll
        for (int k = 0; k < 32; ++k) R[k] = np[k];
#pragma unroll
        for (int d = 0; d < 6; ++d) pd[d] *= rs;
#pragma unroll
        for (int m = 1; m < 16; m <<= 1)
#pragma unroll
            for (int d = 0; d < 6; ++d)
                pd[d] += __shfl_xor(pd[d], m, 16);
        if ((tid & 15) == 0) {
            float* op = out + ((b * 256 + t) * 16 + n) * 6;
#pragma unroll
            for (int d = 0; d < 6; ++d) op[d] = xv[d] + bo[d] + pd[d];
        }
    }
}

extern "C" void kernel_launch(void* const* d_in, const int* in_sizes, int n_in,
                              void* d_out, int out_size, void* d_ws, size_t ws_size,
                              hipStream_t stream) {
    (void)in_sizes; (void)n_in; (void)out_size;
    const float* x     = (const float*)d_in[0];  // [16,256,16,6]
    const float* W_in  = (const float*)d_in[1];  // [6,512]
    const float* b_in  = (const float*)d_in[2];  // [512]
    const float* W_out = (const float*)d_in[3];  // [512,6]
    const float* b_out = (const float*)d_in[4];  // [6]
    float* out = (float*)d_out;                  // [16,256,16,6]

    const size_t qBytes  = 4096UL * 32 * 32 * sizeof(float);       // 16 MB
    const size_t wsBytes = 256UL * 16 * 256 * 6 * sizeof(float);   // 24 MB
    if (ws_size >= qBytes + wsBytes) {
        float* Q   = (float*)d_ws;
        float* WS2 = (float*)((char*)d_ws + qBytes);
        k_seg2  <<<512,  256, 0, stream>>>(x, W_in, b_in, Q);
        k_scan2 <<<512,  256, 0, stream>>>(Q);
        k_apply2<<<512,  256, 0, stream>>>(x, W_in, b_in, W_out, Q, WS2);
        k_reduce<<<1536, 256, 0, stream>>>(x, b_out, WS2, out);
    } else if (ws_size >= qBytes) {
        float* Q = (float*)d_ws;
        k_seg_fb<32>  <<<512, 256, 0, stream>>>(x, W_in, b_in, Q);
        k_scan_fb<32> <<<512, 256, 0, stream>>>(Q);
        k_apply_fb<32><<<512, 256, 0, stream>>>(x, W_in, b_in, W_out, b_out, Q, out);
    } else {
        float* Q = (float*)d_ws;
        k_seg_fb<16>  <<<256, 256, 0, stream>>>(x, W_in, b_in, Q);
        k_scan_fb<16> <<<256, 256, 0, stream>>>(Q);
        k_apply_fb<16><<<256, 256, 0, stream>>>(x, W_in, b_in, W_out, b_out, Q, out);
    }
}